// Round 8
// baseline (499.825 us; speedup 1.0000x reference)
//
#include <hip/hip_runtime.h>

typedef __bf16 bf16_t;
typedef __bf16 bf16x8 __attribute__((ext_vector_type(8)));
typedef __bf16 bf16x4 __attribute__((ext_vector_type(4)));
typedef float f32x4 __attribute__((ext_vector_type(4)));

typedef const __attribute__((address_space(1))) void gv_t;
typedef __attribute__((address_space(3))) void lv_t;

#define NROWS 32768

__device__ __forceinline__ float wave_sum(float v) {
#pragma unroll
  for (int o = 32; o > 0; o >>= 1) v += __shfl_xor(v, o, 64);
  return v;
}

// ====== GEMM1 (fused fp32->bf16 A): C[M,512] = relu(Xf32 @ W1 + b1) ======
// 128x128 tile, 4 waves, 2-phase dbuf. A staged via registers (float4 loads
// for tile t+1 issued BEFORE MFMA of t; cvt+ds_write after -> T14 overlap).
// B staged via global_load_lds. XCD-swizzled grid.
__global__ __launch_bounds__(256) void gemmx_k(
    const float* __restrict__ X, const bf16_t* __restrict__ BT,
    const float* __restrict__ bias, bf16_t* __restrict__ Cp, const int K) {
  __shared__ bf16_t sA[2][128 * 32];
  __shared__ bf16_t sB[2][128 * 32];
  const int tid = threadIdx.x;
  const int lane = tid & 63;
  const int wid = tid >> 6;
  const int wr = wid >> 1;
  const int wc = wid & 1;
  const int bid = blockIdx.x;
  const int work = ((bid & 7) << 7) + (bid >> 3);
  const int bm0 = (work >> 2) * 128;
  const int bn0 = (work & 3) * 128;
  const int N = 512;

  f32x4 acc[4][4];
#pragma unroll
  for (int m = 0; m < 4; ++m)
#pragma unroll
    for (int n = 0; n < 4; ++n) acc[m][n] = f32x4{0.f, 0.f, 0.f, 0.f};

  const int arb = tid >> 3;        // A-load base row (32 rows per pass)
  const int aks = (tid & 7) << 2;  // A-load k offset (4 floats)

  auto loadA = [&](float4* fr, int k0) {
#pragma unroll
    for (int p = 0; p < 4; ++p)
      fr[p] = *(const float4*)(X + (size_t)(bm0 + arb + p * 32) * K + k0 + aks);
  };
  auto writeA = [&](bf16_t* dA, const float4* fr) {
#pragma unroll
    for (int p = 0; p < 4; ++p) {
      bf16x4 w;
      w[0] = (bf16_t)fr[p].x; w[1] = (bf16_t)fr[p].y;
      w[2] = (bf16_t)fr[p].z; w[3] = (bf16_t)fr[p].w;
      *(bf16x4*)(&dA[(arb + p * 32) * 32 + aks]) = w;
    }
  };
  auto stageB = [&](bf16_t* dB, int k0) {
#pragma unroll
    for (int i = 0; i < 2; ++i) {
      const int off = wid * 2048 + i * 1024;
      const int lidx = off + lane * 16;
      const int col = lidx >> 6;
      const int kb = lidx & 63;
      gv_t* src = (gv_t*)((const char*)(BT + (size_t)(bn0 + col) * K + k0) + kb);
      __builtin_amdgcn_global_load_lds(src, (lv_t*)((char*)dB + off), 16, 0, 0);
    }
  };

  {
    float4 fr[4];
    loadA(fr, 0);
    stageB(sB[0], 0);
    writeA(sA[0], fr);
  }
  __syncthreads();
  const int arow = lane & 15;
  const int koff = (lane >> 4) * 8;
  const int nt = K >> 5;
  int cur = 0;
  for (int t = 0; t < nt; ++t) {
    float4 nx[4];
    const bool more = (t + 1 < nt);
    if (more) {
      loadA(nx, (t + 1) << 5);           // in flight during MFMA
      stageB(sB[cur ^ 1], (t + 1) << 5);
    }
    bf16x8 af[4], bg[4];
#pragma unroll
    for (int m = 0; m < 4; ++m)
      af[m] = *(const bf16x8*)&sA[cur][(wr * 64 + m * 16 + arow) * 32 + koff];
#pragma unroll
    for (int n = 0; n < 4; ++n)
      bg[n] = *(const bf16x8*)&sB[cur][(wc * 64 + n * 16 + arow) * 32 + koff];
#pragma unroll
    for (int m = 0; m < 4; ++m)
#pragma unroll
      for (int n = 0; n < 4; ++n)
        acc[m][n] = __builtin_amdgcn_mfma_f32_16x16x32_bf16(af[m], bg[n], acc[m][n], 0, 0, 0);
    if (more) writeA(sA[cur ^ 1], nx);   // compiler waits vmcnt for nx only
    __syncthreads();
    cur ^= 1;
  }

  const int r0 = bm0 + wr * 64 + ((lane >> 4) << 2);
  const int c0 = bn0 + wc * 64 + (lane & 15);
  float bv[4];
#pragma unroll
  for (int n = 0; n < 4; ++n) bv[n] = bias[c0 + n * 16];
#pragma unroll
  for (int m = 0; m < 4; ++m)
#pragma unroll
    for (int n = 0; n < 4; ++n) {
      const size_t base = (size_t)(r0 + m * 16) * N + (c0 + n * 16);
#pragma unroll
      for (int r = 0; r < 4; ++r) {
        float v = acc[m][n][r] + bv[n];
        v = fmaxf(v, 0.f);
        Cp[base + (size_t)r * N] = (bf16_t)v;
      }
    }
}

// ============ GEMM (N=512, bf16 A): 128x128, 4 waves, 2-phase ============
__global__ __launch_bounds__(256) void gemm_k(
    const bf16_t* __restrict__ Ap, const bf16_t* __restrict__ BT,
    const float* __restrict__ bias, bf16_t* __restrict__ Cp, const int K) {
  __shared__ bf16_t sA[2][128 * 32];
  __shared__ bf16_t sB[2][128 * 32];
  const int tid = threadIdx.x;
  const int lane = tid & 63;
  const int wid = tid >> 6;
  const int wr = wid >> 1;
  const int wc = wid & 1;
  const int bid = blockIdx.x;
  const int work = ((bid & 7) << 7) + (bid >> 3);
  const int bm0 = (work >> 2) * 128;
  const int bn0 = (work & 3) * 128;
  const int N = 512;

  f32x4 acc[4][4];
#pragma unroll
  for (int m = 0; m < 4; ++m)
#pragma unroll
    for (int n = 0; n < 4; ++n) acc[m][n] = f32x4{0.f, 0.f, 0.f, 0.f};

  auto stage = [&](bf16_t* dA, bf16_t* dB, int k0) {
#pragma unroll
    for (int i = 0; i < 2; ++i) {
      const int off = wid * 2048 + i * 1024;
      const int lidx = off + lane * 16;
      const int row = lidx >> 6;
      const int kb = lidx & 63;
      gv_t* srcA = (gv_t*)((const char*)(Ap + (size_t)(bm0 + row) * K + k0) + kb);
      __builtin_amdgcn_global_load_lds(srcA, (lv_t*)((char*)dA + off), 16, 0, 0);
      gv_t* srcB = (gv_t*)((const char*)(BT + (size_t)(bn0 + row) * K + k0) + kb);
      __builtin_amdgcn_global_load_lds(srcB, (lv_t*)((char*)dB + off), 16, 0, 0);
    }
  };

  stage(sA[0], sB[0], 0);
  const int arow = lane & 15;
  const int koff = (lane >> 4) * 8;
  const int nt = K >> 5;
  int cur = 0;
  __syncthreads();
  for (int t = 0; t < nt; ++t) {
    if (t + 1 < nt) stage(sA[cur ^ 1], sB[cur ^ 1], (t + 1) << 5);
    bf16x8 af[4], bg[4];
#pragma unroll
    for (int m = 0; m < 4; ++m)
      af[m] = *(const bf16x8*)&sA[cur][(wr * 64 + m * 16 + arow) * 32 + koff];
#pragma unroll
    for (int n = 0; n < 4; ++n)
      bg[n] = *(const bf16x8*)&sB[cur][(wc * 64 + n * 16 + arow) * 32 + koff];
#pragma unroll
    for (int m = 0; m < 4; ++m)
#pragma unroll
      for (int n = 0; n < 4; ++n)
        acc[m][n] = __builtin_amdgcn_mfma_f32_16x16x32_bf16(af[m], bg[n], acc[m][n], 0, 0, 0);
    __syncthreads();
    cur ^= 1;
  }

  const int r0 = bm0 + wr * 64 + ((lane >> 4) << 2);
  const int c0 = bn0 + wc * 64 + (lane & 15);
  float bv[4];
#pragma unroll
  for (int n = 0; n < 4; ++n) bv[n] = bias[c0 + n * 16];
#pragma unroll
  for (int m = 0; m < 4; ++m)
#pragma unroll
    for (int n = 0; n < 4; ++n) {
      const size_t base = (size_t)(r0 + m * 16) * N + (c0 + n * 16);
#pragma unroll
      for (int r = 0; r < 4; ++r) {
        float v = acc[m][n][r] + bv[n];
        v = fmaxf(v, 0.f);
        Cp[base + (size_t)r * N] = (bf16_t)v;
      }
    }
}

// ============ Wide GEMM (N=256 full-row tile): 128x256, 8 waves ============
// EPI 1: acc+bias -> f32. EPI 2: normalize fusion. EPI 3: geometry fusion.
template <int EPI>
__global__ __launch_bounds__(512) void wgemm_k(
    const bf16_t* __restrict__ Ap, const bf16_t* __restrict__ BT,
    const float* __restrict__ bias, float* __restrict__ Cp, const int K,
    float* __restrict__ mp_out, bf16_t* __restrict__ mpb,
    float* __restrict__ colsum, const float* __restrict__ center,
    const float* __restrict__ cMv, bf16_t* __restrict__ gf,
    float* __restrict__ accum) {
  __shared__ bf16_t sA[2][128 * 32];
  __shared__ bf16_t sB[2][256 * 32];
  const int tid = threadIdx.x;
  const int lane = tid & 63;
  const int wid = tid >> 6;
  const int bm0 = blockIdx.x * 128;

  f32x4 acc[16];
#pragma unroll
  for (int n = 0; n < 16; ++n) acc[n] = f32x4{0.f, 0.f, 0.f, 0.f};

  auto stage = [&](bf16_t* dA, bf16_t* dB, int k0) {
    {
      const int off = wid * 1024;
      const int lidx = off + lane * 16;
      const int row = lidx >> 6;
      const int kb = lidx & 63;
      gv_t* src = (gv_t*)((const char*)(Ap + (size_t)(bm0 + row) * K + k0) + kb);
      __builtin_amdgcn_global_load_lds(src, (lv_t*)((char*)dA + off), 16, 0, 0);
    }
#pragma unroll
    for (int i = 0; i < 2; ++i) {
      const int off = wid * 2048 + i * 1024;
      const int lidx = off + lane * 16;
      const int col = lidx >> 6;
      const int kb = lidx & 63;
      gv_t* src = (gv_t*)((const char*)(BT + (size_t)col * K + k0) + kb);
      __builtin_amdgcn_global_load_lds(src, (lv_t*)((char*)dB + off), 16, 0, 0);
    }
  };

  stage(sA[0], sB[0], 0);
  const int arow = lane & 15;
  const int koff = (lane >> 4) * 8;
  const int nt = K >> 5;
  int cur = 0;
  __syncthreads();
  for (int t = 0; t < nt; ++t) {
    if (t + 1 < nt) stage(sA[cur ^ 1], sB[cur ^ 1], (t + 1) << 5);
    bf16x8 af = *(const bf16x8*)&sA[cur][(wid * 16 + arow) * 32 + koff];
#pragma unroll
    for (int n = 0; n < 16; ++n) {
      bf16x8 bg = *(const bf16x8*)&sB[cur][(n * 16 + arow) * 32 + koff];
      acc[n] = __builtin_amdgcn_mfma_f32_16x16x32_bf16(af, bg, acc[n], 0, 0, 0);
    }
    __syncthreads();
    cur ^= 1;
  }

  const int cl = lane & 15;
  const int rg = (lane >> 4) << 2;

  if constexpr (EPI == 1) {
    float bv[16];
#pragma unroll
    for (int n = 0; n < 16; ++n) bv[n] = bias[n * 16 + cl];
#pragma unroll
    for (int r = 0; r < 4; ++r) {
      const int row = bm0 + wid * 16 + rg + r;
      const size_t rb = (size_t)row * 256 + cl;
#pragma unroll
      for (int n = 0; n < 16; ++n) Cp[rb + n * 16] = acc[n][r] + bv[n];
    }
  }

  if constexpr (EPI == 2) {
    float bv[16], cs[16];
#pragma unroll
    for (int n = 0; n < 16; ++n) { bv[n] = bias[n * 16 + cl]; cs[n] = 0.f; }
#pragma unroll
    for (int r = 0; r < 4; ++r) {
      const int row = bm0 + wid * 16 + rg + r;
      float v[16];
      float ss = 0.f;
#pragma unroll
      for (int n = 0; n < 16; ++n) { v[n] = acc[n][r] + bv[n]; ss += v[n] * v[n]; }
#pragma unroll
      for (int o = 1; o < 16; o <<= 1) ss += __shfl_xor(ss, o, 64);
      const float inv = 1.f / fmaxf(sqrtf(ss), 1e-12f);
      const size_t rb = (size_t)row * 256 + cl;
#pragma unroll
      for (int n = 0; n < 16; ++n) {
        const float m = v[n] * inv;
        mp_out[rb + n * 16] = m;
        mpb[rb + n * 16] = (bf16_t)m;
        cs[n] += m;
      }
    }
#pragma unroll
    for (int n = 0; n < 16; ++n) {
      cs[n] += __shfl_xor(cs[n], 16, 64);
      cs[n] += __shfl_xor(cs[n], 32, 64);
    }
    __shared__ float scs[256];
    if (tid < 256) scs[tid] = 0.f;
    __syncthreads();
    if (lane < 16) {
#pragma unroll
      for (int n = 0; n < 16; ++n) atomicAdd(&scs[n * 16 + lane], cs[n]);
    }
    __syncthreads();
    if (tid < 256) atomicAdd(&colsum[tid], scs[tid]);
  }

  if constexpr (EPI == 3) {
    float c[16], q[16];
#pragma unroll
    for (int n = 0; n < 16; ++n) { c[n] = center[n * 16 + cl]; q[n] = cMv[n * 16 + cl]; }
    float a_d = 0.f, a_d2 = 0.f, a_tn = 0.f;
#pragma unroll
    for (int r = 0; r < 4; ++r) {
      const int row = bm0 + wid * 16 + rg + r;
      const size_t rb = (size_t)row * 256 + cl;
      float mpv[16];
      float pd = 0.f, pp = 0.f;
#pragma unroll
      for (int n = 0; n < 16; ++n) {
        mpv[n] = mp_out[rb + n * 16];
        const float d = mpv[n] - c[n];
        const float e = acc[n][r] - q[n];
        pd += d * e;
        pp += d * c[n];
      }
#pragma unroll
      for (int o = 1; o < 16; o <<= 1) {
        pd += __shfl_xor(pd, o, 64);
        pp += __shfl_xor(pp, o, 64);
      }
      float ptn = 0.f;
#pragma unroll
      for (int n = 0; n < 16; ++n) {
        const float d = mpv[n] - c[n];
        const float t = d - pp * c[n];
        ptn += t * t;
        gf[rb + n * 16] = (bf16_t)(mpv[n] + 0.1f * t);
      }
#pragma unroll
      for (int o = 1; o < 16; o <<= 1) ptn += __shfl_xor(ptn, o, 64);
      if (cl == 0) {
        const float dist = sqrtf(fmaxf(pd, 0.f));
        a_d += dist - 1.f;                     // shifted accumulation
        a_d2 += (dist - 1.f) * (dist - 1.f);
        a_tn += sqrtf(fmaxf(ptn, 0.f));
      }
    }
    a_d += __shfl_xor(a_d, 16, 64);  a_d += __shfl_xor(a_d, 32, 64);
    a_d2 += __shfl_xor(a_d2, 16, 64); a_d2 += __shfl_xor(a_d2, 32, 64);
    a_tn += __shfl_xor(a_tn, 16, 64); a_tn += __shfl_xor(a_tn, 32, 64);
    __shared__ float sa[3][8];
    if (lane == 0) { sa[0][wid] = a_d; sa[1][wid] = a_d2; sa[2][wid] = a_tn; }
    __syncthreads();
    if (tid == 0) {
      float s0 = 0.f, s1 = 0.f, s2 = 0.f;
#pragma unroll
      for (int w = 0; w < 8; ++w) { s0 += sa[0][w]; s1 += sa[1][w]; s2 += sa[2][w]; }
      atomicAdd(&accum[1], s0);
      atomicAdd(&accum[2], s1);
      atomicAdd(&accum[3], s2);
    }
  }
}

// -- setup: conn abs-sum (blocks 0..511) + LDS-tiled weight transpose --
__global__ __launch_bounds__(256) void setup_k(
    const float* __restrict__ conn, float* __restrict__ accum,
    const float* __restrict__ W1, bf16_t* __restrict__ W1T,
    const float* __restrict__ W2, bf16_t* __restrict__ W2T,
    const float* __restrict__ metric, bf16_t* __restrict__ MT,
    const float* __restrict__ W3, bf16_t* __restrict__ W3T,
    const float* __restrict__ W4, bf16_t* __restrict__ W4T) {
  const int b = blockIdx.x, tid = threadIdx.x;
  if (b < 512) {
    __shared__ float sw[4];
    const float4* src = (const float4*)conn + (size_t)b * 8192;
    float s0 = 0.f, s1 = 0.f;
    for (int i = tid; i < 8192; i += 512) {  // 2 independent loads per iter
      const float4 u = src[i];
      const float4 v = src[i + 256];
      s0 += fabsf(u.x) + fabsf(u.y) + fabsf(u.z) + fabsf(u.w);
      s1 += fabsf(v.x) + fabsf(v.y) + fabsf(v.z) + fabsf(v.w);
    }
    float s = wave_sum(s0 + s1);
    if ((tid & 63) == 0) sw[tid >> 6] = s;
    __syncthreads();
    if (tid == 0) atomicAdd(&accum[0], sw[0] + sw[1] + sw[2] + sw[3]);
  } else {
    // 64x64 LDS tile transpose, fp32 in -> bf16 out, both sides coalesced.
    int t = b - 512;
    const float* S; bf16_t* D; int R, C;
    if (t < 128)      { S = W1;     D = W1T; R = 1024; C = 512; }
    else if (t < 160) { S = W2;     D = W2T; R = 512;  C = 256; t -= 128; }
    else if (t < 176) { S = metric; D = MT;  R = 256;  C = 256; t -= 160; }
    else if (t < 208) { S = W3;     D = W3T; R = 256;  C = 512; t -= 176; }
    else              { S = W4;     D = W4T; R = 512;  C = 256; t -= 208; }
    const int tpr = C >> 6;
    const int tr = t / tpr, tc = t % tpr;
    __shared__ float tile[64][65];
    const int c4 = (tid & 15) << 2;
    const int r0 = tid >> 4;
#pragma unroll
    for (int p = 0; p < 4; ++p) {
      const int r = r0 + p * 16;
      const float4 v = *(const float4*)(S + (size_t)(tr * 64 + r) * C + tc * 64 + c4);
      tile[r][c4] = v.x; tile[r][c4 + 1] = v.y;
      tile[r][c4 + 2] = v.z; tile[r][c4 + 3] = v.w;
    }
    __syncthreads();
    const int rr = (tid & 15) << 2;
    const int cc = tid >> 4;
#pragma unroll
    for (int p = 0; p < 4; ++p) {
      const int c = cc + p * 16;
      bf16x4 w;
      w[0] = (bf16_t)tile[rr][c];     w[1] = (bf16_t)tile[rr + 1][c];
      w[2] = (bf16_t)tile[rr + 2][c]; w[3] = (bf16_t)tile[rr + 3][c];
      *(bf16x4*)(D + (size_t)(tc * 64 + c) * R + tr * 64 + rr) = w;
    }
  }
}

// -------- center = colsum/B ; cM = center @ metric --------
__global__ void center_k(const float* __restrict__ colsum,
                         const float* __restrict__ metric,
                         float* __restrict__ center, float* __restrict__ cMv) {
  const int j = threadIdx.x;
  __shared__ float sc[256];
  const float c = colsum[j] * (1.f / 32768.f);
  center[j] = c;
  sc[j] = c;
  __syncthreads();
  float a = 0.f;
  for (int k = 0; k < 256; ++k) a += sc[k] * metric[k * 256 + j];
  cMv[j] = a;
}

__global__ void finalize_k(const float* __restrict__ accum, float* __restrict__ out) {
  if (threadIdx.x == 0) {
    const float Bf = 32768.f;
    const float sd = accum[1], sd2 = accum[2], stn = accum[3], cs = accum[0];
    out[8388608] = 1.f + sd / Bf;              // manifold_distance
    out[8388609] = cs * (1.f / 256.f);         // curvature_magnitude
    out[8388610] = stn / Bf;                   // tangent_norm
    const float var = (sd2 - sd * sd / Bf) / (Bf - 1.f);
    out[16777219] = sqrtf(fmaxf(var, 0.f));    // geometric_complexity
  }
}

extern "C" void kernel_launch(void* const* d_in, const int* in_sizes, int n_in,
                              void* d_out, int out_size, void* d_ws, size_t ws_size,
                              hipStream_t stream) {
  const float* x = (const float*)d_in[0];
  const float* W1 = (const float*)d_in[1];
  const float* b1 = (const float*)d_in[2];
  const float* W2 = (const float*)d_in[3];
  const float* b2 = (const float*)d_in[4];
  const float* metric = (const float*)d_in[5];
  const float* conn = (const float*)d_in[6];
  const float* W3 = (const float*)d_in[7];
  const float* b3 = (const float*)d_in[8];
  const float* W4 = (const float*)d_in[9];
  const float* b4 = (const float*)d_in[10];
  float* out_f = (float*)d_out;
  float* mp_out = out_f + 8388611;  // normalized mp lives in d_out directly

  char* ws = (char*)d_ws;
  float* accum = (float*)(ws + 0);          // [0]=conn_sum [1]=sd [2]=sd2 [3]=stn
  float* colsum = (float*)(ws + 256);
  float* center = (float*)(ws + 1280);
  float* cMv = (float*)(ws + 2304);
  bf16_t* W1T = (bf16_t*)(ws + 4096);
  bf16_t* W2T = (bf16_t*)(ws + 1052672);
  bf16_t* MT = (bf16_t*)(ws + 1314816);
  bf16_t* W3T = (bf16_t*)(ws + 1445888);
  bf16_t* W4T = (bf16_t*)(ws + 1708032);
  bf16_t* hB = (bf16_t*)(ws + 2097152);     // 33.5 MB
  bf16_t* g2 = (bf16_t*)(ws + 35651584);    // 33.5 MB
  bf16_t* mpb = (bf16_t*)(ws + 69206016);   // 16.8 MB
  bf16_t* gf = (bf16_t*)(ws + 85983232);    // 16.8 MB (ends 102760448)

  hipMemsetAsync(d_ws, 0, 4096, stream);
  setup_k<<<752, 256, 0, stream>>>(conn, accum, W1, W1T, W2, W2T, metric, MT,
                                   W3, W3T, W4, W4T);
  // h = relu(x @ W1 + b1)   [32768,512] bf16  (fp32 A converted in-pipeline)
  gemmx_k<<<1024, 256, 0, stream>>>(x, W1T, b1, hB, 1024);
  // mp = normalize(h @ W2 + b2)  -> mp_out(f32) + mpb(bf16) + colsum
  wgemm_k<2><<<256, 512, 0, stream>>>(hB, W2T, b2, nullptr, 512, mp_out, mpb,
                                      colsum, nullptr, nullptr, nullptr, nullptr);
  center_k<<<1, 256, 0, stream>>>(colsum, metric, center, cMv);
  // acc = mp @ metric ; fused distances/tangent/gf/stats
  wgemm_k<3><<<256, 512, 0, stream>>>(mpb, MT, nullptr, nullptr, 256, mp_out,
                                      nullptr, nullptr, center, cMv, gf, accum);
  // g2 = relu(gf @ W3 + b3) [32768,512] bf16
  gemm_k<<<1024, 256, 0, stream>>>(gf, W3T, b3, g2, 256);
  // out = g2 @ W4 + b4      [32768,256] f32 -> d_out
  wgemm_k<1><<<256, 512, 0, stream>>>(g2, W4T, b4, out_f, 512, nullptr, nullptr,
                                      nullptr, nullptr, nullptr, nullptr, nullptr);
  finalize_k<<<1, 64, 0, stream>>>(accum, out_f);
}